// Round 2
// baseline (252.180 us; speedup 1.0000x reference)
//
#include <hip/hip_runtime.h>
#include <hip/hip_bf16.h>
#include <stdint.h>

// PointNet EdgeConv, 2 layers. Round 17.
// R10: atomic-free bucket sort + MFMA edge_seg.                278 us
// R13: U table packed bf16 (gather 128 -> 64 B).               257 us
// R14: cvt_pk_bf16 + bf16 m-matrix + bias-in-C.                233 us
// R15: fused setup; 512-edge edge_seg blocks.                  230 us <- best
// R16: direct-to-fragment gathers in edge_seg.                 237 us
// R17: range-bucket edge kernel. One block per 128-dst range (the
//      granularity bucket_scatter already emits). Segmented max becomes a
//      16KB LDS atomicMax table with exclusive writeout ->
//      * bucket_sort kernel deleted (no within-range sort needed)
//      * agg-init + finalize kernels deleted (blocks write relu'd float
//        exclusively; -inf decodes to 0 for isolated nodes)
//      * global atomicMax straddlers deleted
//      * m-matrix LDS + phase-2 deleted; dst via __shfl of this wave's own
//        edge descriptors (C-row rr -> edge offset (rr&3)+8(rr>>2)+4h)
//      * barrier-free chunk loop (atomics are the only cross-wave dep)
//      Max now over f32 MFMA outputs (no bf16 m rounding) -> >= accuracy.

#define BS 256
#define EBS 512        // edge kernel block size (512 edges per chunk)
#define K1_EDGES 4096  // edges staged per block in scatter pass

typedef float v2f __attribute__((ext_vector_type(2)));
typedef __attribute__((ext_vector_type(8))) short bf16x8;
typedef __attribute__((ext_vector_type(16))) float f32x16;
typedef __bf16 bf16v2 __attribute__((ext_vector_type(2)));

__device__ __forceinline__ unsigned ordenc(float f) {
    unsigned u = __float_as_uint(f);
    return (u & 0x80000000u) ? ~u : (u | 0x80000000u);
}
__device__ __forceinline__ float orddec(unsigned o) {
    unsigned u = (o & 0x80000000u) ? (o ^ 0x80000000u) : ~o;
    return __uint_as_float(u);
}
#define ORD_NEG_INF 0x007FFFFFu  // ordenc(-inf)

// two f32 -> packed bf16 pair (RNE) via v_cvt_pk_bf16_f32; x -> low half
__device__ __forceinline__ unsigned cvt2(float x, float y) {
    v2f v = {x, y};
    bf16v2 b = __builtin_convertvector(v, bf16v2);
    return __builtin_bit_cast(unsigned, b);
}
__device__ __forceinline__ float bflo(unsigned u) { return __uint_as_float(u << 16); }
__device__ __forceinline__ float bfhi(unsigned u) { return __uint_as_float(u & 0xFFFF0000u); }

// build 8 channels of h = relu(bf16(U) - V) as 4 packed bf16 pairs
__device__ __forceinline__ uint4 mk_frag(uint4 ua, float4 v0, float4 v1) {
    uint4 o;
    o.x = cvt2(fmaxf(bflo(ua.x) - v0.x, 0.0f), fmaxf(bfhi(ua.x) - v0.y, 0.0f));
    o.y = cvt2(fmaxf(bflo(ua.y) - v0.z, 0.0f), fmaxf(bfhi(ua.y) - v0.w, 0.0f));
    o.z = cvt2(fmaxf(bflo(ua.z) - v1.x, 0.0f), fmaxf(bfhi(ua.z) - v1.y, 0.0f));
    o.w = cvt2(fmaxf(bflo(ua.w) - v1.z, 0.0f), fmaxf(bfhi(ua.w) - v1.w, 0.0f));
    return o;
}

// ---------------- fused setup: range-hist | prep1 | Wbt pack ----------------
// Blocks [0, NB1)       : per-block range histogram of dst>>7
// Blocks [NB1, NB1+NBn) : prep1 (U bf16 / V f32 for layer 1)
// Last block            : pack per-lane B fragments for both layers
__global__ __launch_bounds__(BS) void setup_kernel(
    const int* __restrict__ ei, int E, int NRP, int* __restrict__ blockHist,
    const float* __restrict__ pos, const float* __restrict__ Wa, const float* __restrict__ ba,
    unsigned* __restrict__ Ubf, float* __restrict__ V, int N, int NB1, int NBn,
    const float* __restrict__ Wb2, const float* __restrict__ Wb4,
    unsigned* __restrict__ WbtG) {
    __shared__ int hist[1024];
    const int tid = threadIdx.x;
    const int b = blockIdx.x;
    if (b < NB1) {
        for (int r = tid; r < 1024; r += BS) hist[r] = 0;
        __syncthreads();
        const int base = b * K1_EDGES;
        const int M = min(K1_EDGES, E - base);
        for (int i = tid; i < M; i += BS) atomicAdd(&hist[ei[E + base + i] >> 7], 1);
        __syncthreads();
        for (int r = tid; r < NRP; r += BS) blockHist[b * NRP + r] = hist[r];
    } else if (b < NB1 + NBn) {
        const int n = (b - NB1) * BS + tid;
        if (n >= N) return;
        const float p[3] = {pos[3 * n], pos[3 * n + 1], pos[3 * n + 2]};
        v2f u[16], v[16];
#pragma unroll
        for (int g = 0; g < 16; ++g) {
            u[g] = *reinterpret_cast<const v2f*>(&ba[g * 2]);
            v2f z = {0.0f, 0.0f};
            v[g] = z;
        }
#pragma unroll
        for (int i = 0; i < 3; ++i) {
            const v2f f = {p[i], p[i]};
#pragma unroll
            for (int g = 0; g < 16; ++g) {
                const v2f wA = *reinterpret_cast<const v2f*>(&Wa[i * 32 + g * 2]);
                const v2f wB = *reinterpret_cast<const v2f*>(&Wa[(i + 3) * 32 + g * 2]);
                u[g] = __builtin_elementwise_fma(f, wA + wB, u[g]);
                v[g] = __builtin_elementwise_fma(f, wB, v[g]);
            }
        }
        uint4* Up = reinterpret_cast<uint4*>(Ubf + (size_t)n * 16);
        float4* Vp = reinterpret_cast<float4*>(V + (size_t)n * 32);
#pragma unroll
        for (int q = 0; q < 4; ++q) {
            uint4 o;
            o.x = cvt2(u[4 * q + 0].x, u[4 * q + 0].y);
            o.y = cvt2(u[4 * q + 1].x, u[4 * q + 1].y);
            o.z = cvt2(u[4 * q + 2].x, u[4 * q + 2].y);
            o.w = cvt2(u[4 * q + 3].x, u[4 * q + 3].y);
            Up[q] = o;
        }
#pragma unroll
        for (int q = 0; q < 8; ++q)
            Vp[q] = make_float4(v[2 * q].x, v[2 * q].y, v[2 * q + 1].x, v[2 * q + 1].y);
    } else {
        // pack per-lane B fragments (bf16 pairs) for both layers: 2 x 512 dw
        if (tid < 128) {
            const int layer = tid >> 6;
            const int t = tid & 63;
            const int lnp = t & 31;
            const int hp = t >> 5;
            const float* Wb = layer ? Wb4 : Wb2;
            unsigned* dst = WbtG + layer * 512 + t * 8;
#pragma unroll
            for (int q = 0; q < 4; ++q) {
                const int p = 4 * hp + q;
                dst[q] = cvt2(Wb[(2 * p) * 32 + lnp], Wb[(2 * p + 1) * 32 + lnp]);
                dst[4 + q] = cvt2(Wb[(2 * p + 16) * 32 + lnp], Wb[(2 * p + 17) * 32 + lnp]);
            }
        }
    }
}

// ---------------- pass 2a: per-(block,range) LOCAL prefixes + range totals --
__global__ __launch_bounds__(512) void off_scan_kernel(const int* __restrict__ blockHist,
                                                       int NB1, int NRP,
                                                       int* __restrict__ off,
                                                       int* __restrict__ total) {
    const int r = (blockIdx.x * 512 + threadIdx.x) >> 6;
    const int lane = threadIdx.x & 63;
    if (r >= NRP) return;
    int carry = 0;
    const int chunks = (NB1 + 63) / 64;
    for (int c = 0; c < chunks; ++c) {
        const int b = c * 64 + lane;
        const int v = (b < NB1) ? blockHist[b * NRP + r] : 0;
        int x = v;
#pragma unroll
        for (int d = 1; d < 64; d <<= 1) {
            int y = __shfl_up(x, d, 64);
            if (lane >= d) x += y;
        }
        if (b < NB1) off[b * NRP + r] = carry + (x - v);
        carry += __shfl(x, 63, 64);
    }
    if (lane == 0) total[r] = carry;
}

// ---------------- pass 2b: exclusive scan of totals -> rangeBase ------------
__global__ __launch_bounds__(1024) void range_scan_kernel(const int* __restrict__ total,
                                                          int NRP, int* __restrict__ rangeBase) {
    __shared__ int s[1024];
    const int t = threadIdx.x;
    const int v = (t < NRP) ? total[t] : 0;
    s[t] = v;
    __syncthreads();
    for (int off = 1; off < 1024; off <<= 1) {
        int add = (t >= off) ? s[t - off] : 0;
        __syncthreads();
        s[t] += add;
        __syncthreads();
    }
    if (t < NRP) rangeBase[t] = s[t] - v;
}

// ---------------- pass 1b: LDS-ranked scatter into range buckets ------------
__global__ __launch_bounds__(BS) void bucket_scatter_kernel(
    const int* __restrict__ ei, int E, int NRP, const int* __restrict__ off,
    const int* __restrict__ rangeBase, int2* __restrict__ sedgeB) {
    __shared__ int2 stage[K1_EDGES];          // 32 KB
    __shared__ unsigned short inv[K1_EDGES];  // 8 KB
    __shared__ int hist[1024], start[1024], cursor[1024];
    __shared__ int ts[BS];
    const int tid = threadIdx.x;
    for (int r = tid; r < 1024; r += BS) hist[r] = 0;
    __syncthreads();
    const int base = blockIdx.x * K1_EDGES;
    const int M = min(K1_EDGES, E - base);
    for (int i = tid; i < M; i += BS) {
        const int2 p = make_int2(ei[base + i], ei[E + base + i]);
        stage[i] = p;
        atomicAdd(&hist[p.y >> 7], 1);
    }
    __syncthreads();
    {
        const int i0 = tid * 4;
        const int l0 = hist[i0], l1 = hist[i0 + 1], l2 = hist[i0 + 2], l3 = hist[i0 + 3];
        const int tsum = l0 + l1 + l2 + l3;
        ts[tid] = tsum;
        __syncthreads();
        for (int off2 = 1; off2 < BS; off2 <<= 1) {
            int add = (tid >= off2) ? ts[tid - off2] : 0;
            __syncthreads();
            ts[tid] += add;
            __syncthreads();
        }
        const int texcl = ts[tid] - tsum;
        start[i0] = texcl;
        start[i0 + 1] = texcl + l0;
        start[i0 + 2] = texcl + l0 + l1;
        start[i0 + 3] = texcl + l0 + l1 + l2;
        cursor[i0] = start[i0];
        cursor[i0 + 1] = start[i0 + 1];
        cursor[i0 + 2] = start[i0 + 2];
        cursor[i0 + 3] = start[i0 + 3];
    }
    __syncthreads();
    for (int i = tid; i < M; i += BS) {
        const int pos = atomicAdd(&cursor[stage[i].y >> 7], 1);
        inv[pos] = (unsigned short)i;
    }
    __syncthreads();
    const int* offb = off + blockIdx.x * NRP;
    for (int j = tid; j < M; j += BS) {
        const int2 p = stage[inv[j]];
        const int r = p.y >> 7;
        sedgeB[rangeBase[r] + offb[r] + (j - start[r])] = p;  // contiguous runs
    }
}

// Layer 2 prep: reads layer-1 agg as plain float (already relu'd).
__global__ __launch_bounds__(BS) void prep2_kernel(const float* __restrict__ pos,
                                                   const float* __restrict__ aggA,
                                                   const float* __restrict__ Wa,
                                                   const float* __restrict__ ba,
                                                   unsigned* __restrict__ Ubf,
                                                   float* __restrict__ V, int N) {
    int n = blockIdx.x * BS + threadIdx.x;
    if (n >= N) return;
    float h[32];
    const float4* hp = reinterpret_cast<const float4*>(aggA + (size_t)n * 32);
#pragma unroll
    for (int q = 0; q < 8; ++q) {
        float4 t = hp[q];
        h[4 * q + 0] = t.x;
        h[4 * q + 1] = t.y;
        h[4 * q + 2] = t.z;
        h[4 * q + 3] = t.w;
    }
    const float p[3] = {pos[3 * n], pos[3 * n + 1], pos[3 * n + 2]};
    v2f u[16], v[16];
#pragma unroll
    for (int g = 0; g < 16; ++g) {
        u[g] = *reinterpret_cast<const v2f*>(&ba[g * 2]);
        v2f z = {0.0f, 0.0f};
        v[g] = z;
    }
#pragma unroll
    for (int i = 0; i < 32; ++i) {
        const v2f f = {h[i], h[i]};
#pragma unroll
        for (int g = 0; g < 16; ++g) {
            const v2f w = *reinterpret_cast<const v2f*>(&Wa[i * 32 + g * 2]);
            u[g] = __builtin_elementwise_fma(f, w, u[g]);
        }
    }
#pragma unroll
    for (int i = 0; i < 3; ++i) {
        const v2f f = {p[i], p[i]};
#pragma unroll
        for (int g = 0; g < 16; ++g) {
            const v2f w = *reinterpret_cast<const v2f*>(&Wa[(32 + i) * 32 + g * 2]);
            u[g] = __builtin_elementwise_fma(f, w, u[g]);
            v[g] = __builtin_elementwise_fma(f, w, v[g]);
        }
    }
    uint4* Up = reinterpret_cast<uint4*>(Ubf + (size_t)n * 16);
    float4* Vp = reinterpret_cast<float4*>(V + (size_t)n * 32);
#pragma unroll
    for (int q = 0; q < 4; ++q) {
        uint4 o;
        o.x = cvt2(u[4 * q + 0].x, u[4 * q + 0].y);
        o.y = cvt2(u[4 * q + 1].x, u[4 * q + 1].y);
        o.z = cvt2(u[4 * q + 2].x, u[4 * q + 2].y);
        o.w = cvt2(u[4 * q + 3].x, u[4 * q + 3].y);
        Up[q] = o;
    }
#pragma unroll
    for (int q = 0; q < 8; ++q)
        Vp[q] = make_float4(v[2 * q].x, v[2 * q].y, v[2 * q + 1].x, v[2 * q + 1].y);
}

// ---------------- range-bucket edge kernel ----------------------------------
// One block per range of 128 dsts (edges pre-grouped by bucket_scatter).
// Chunks of 512 edges: direct-to-fragment gather -> MFMA -> LDS atomicMax
// into aggL[dstLocal][ch]. dst per C-row via __shfl of this wave's own edge
// descriptors. Exclusive writeout: relu'd float, no init / no global atomics.
__global__ __launch_bounds__(EBS, 6) void edge_range_kernel(
    const unsigned* __restrict__ Ubf, const float4* __restrict__ V,
    const int2* __restrict__ sedgeB, const int* __restrict__ rangeBase,
    const int* __restrict__ total, const unsigned* __restrict__ WbtG,
    const float* __restrict__ bb, float* __restrict__ out, int N) {
    __shared__ unsigned aggL[4096];  // [128 dst][32 ch], 16 KB

    const int tid = threadIdx.x;
    const int r = blockIdx.x;
    const int base = rangeBase[r];
    const int M = total[r];

    const int l = tid & 63;
    const int w = tid >> 6;  // 0..7: wave w owns chunk edges [64w, 64w+64)
    const int half = l >> 5;
    const int ln = l & 31;

#pragma unroll
    for (int i = 0; i < 8; ++i) aggL[tid + i * EBS] = ORD_NEG_INF;

    // B fragments: precomputed per-lane packed bf16 (L1-hot, 2 loads)
    const uint4 bu0 = *reinterpret_cast<const uint4*>(WbtG + l * 8);
    const uint4 bu1 = *reinterpret_cast<const uint4*>(WbtG + l * 8 + 4);
    const float bbn = bb[ln];
    __syncthreads();  // aggL init visible before any atomics

    const int nch = (M + EBS - 1) >> 9;
    for (int c = 0; c < nch; ++c) {
        const int cb = c << 9;
        const int last = M - 1;
        const int j0 = min(cb + 64 * w + ln, last);  // this lane's edge pair
        const int j1 = min(j0 + 32, last);           // (dups at tail: ok for max)
        const int2 edA = sedgeB[base + j0];
        const int2 edB = sedgeB[base + j1];

        uint4 au00, au01, au10, au11;
        {
            const uint4* Up = reinterpret_cast<const uint4*>(Ubf + (size_t)edA.x * 16);
            const float4* Vp = V + (size_t)edA.y * 8;
            au00 = mk_frag(Up[half], Vp[2 * half], Vp[2 * half + 1]);
            au01 = mk_frag(Up[2 + half], Vp[4 + 2 * half], Vp[5 + 2 * half]);
        }
        {
            const uint4* Up = reinterpret_cast<const uint4*>(Ubf + (size_t)edB.x * 16);
            const float4* Vp = V + (size_t)edB.y * 8;
            au10 = mk_frag(Up[half], Vp[2 * half], Vp[2 * half + 1]);
            au11 = mk_frag(Up[2 + half], Vp[4 + 2 * half], Vp[5 + 2 * half]);
        }

        f32x16 c0, c1;
#pragma unroll
        for (int i = 0; i < 16; ++i) {
            c0[i] = bbn;
            c1[i] = bbn;
        }
        c0 = __builtin_amdgcn_mfma_f32_32x32x16_bf16(__builtin_bit_cast(bf16x8, au00),
                                                     __builtin_bit_cast(bf16x8, bu0), c0, 0, 0, 0);
        c0 = __builtin_amdgcn_mfma_f32_32x32x16_bf16(__builtin_bit_cast(bf16x8, au01),
                                                     __builtin_bit_cast(bf16x8, bu1), c0, 0, 0, 0);
        c1 = __builtin_amdgcn_mfma_f32_32x32x16_bf16(__builtin_bit_cast(bf16x8, au10),
                                                     __builtin_bit_cast(bf16x8, bu0), c1, 0, 0, 0);
        c1 = __builtin_amdgcn_mfma_f32_32x32x16_bf16(__builtin_bit_cast(bf16x8, au11),
                                                     __builtin_bit_cast(bf16x8, bu1), c1, 0, 0, 0);

        // scatter-max: C row rr <-> edge offset eo = (rr&3)+8(rr>>2)+4h in
        // [0,32) held by lane eo (c0) / +32 held as edB by lane eo (c1).
        // aggL addr (dl<<5)|ln: 32 lanes of a half -> same row, banks 0..31.
#pragma unroll
        for (int rr = 0; rr < 16; ++rr) {
            const int eo = (rr & 3) + 8 * (rr >> 2) + 4 * half;
            const int d0 = __shfl(edA.y, eo, 64);
            const int d1 = __shfl(edB.y, eo, 64);
            atomicMax(&aggL[((d0 & 127) << 5) | ln], ordenc(c0[rr]));
            atomicMax(&aggL[((d1 & 127) << 5) | ln], ordenc(c1[rr]));
        }
    }
    __syncthreads();

    // exclusive writeout: 4096 values, 8 per thread, decode + relu -> float
    const int idx = tid * 8;
    const int node = (r << 7) + (idx >> 5);
    if (node < N) {
        float4 o0, o1;
        o0.x = fmaxf(orddec(aggL[idx + 0]), 0.0f);
        o0.y = fmaxf(orddec(aggL[idx + 1]), 0.0f);
        o0.z = fmaxf(orddec(aggL[idx + 2]), 0.0f);
        o0.w = fmaxf(orddec(aggL[idx + 3]), 0.0f);
        o1.x = fmaxf(orddec(aggL[idx + 4]), 0.0f);
        o1.y = fmaxf(orddec(aggL[idx + 5]), 0.0f);
        o1.z = fmaxf(orddec(aggL[idx + 6]), 0.0f);
        o1.w = fmaxf(orddec(aggL[idx + 7]), 0.0f);
        float4* op = reinterpret_cast<float4*>(out + (size_t)node * 32 + (idx & 31));
        op[0] = o0;
        op[1] = o1;
    }
}

extern "C" void kernel_launch(void* const* d_in, const int* in_sizes, int n_in,
                              void* d_out, int out_size, void* d_ws, size_t ws_size,
                              hipStream_t stream) {
    const float* pos = (const float*)d_in[0];
    const int* ei = (const int*)d_in[1];
    const float* W1 = (const float*)d_in[3];
    const float* b1 = (const float*)d_in[4];
    const float* W2 = (const float*)d_in[5];
    const float* b2 = (const float*)d_in[6];
    const float* W3 = (const float*)d_in[7];
    const float* b3 = (const float*)d_in[8];
    const float* W4 = (const float*)d_in[9];
    const float* b4 = (const float*)d_in[10];

    const int E = in_sizes[1] / 2;
    const int N = in_sizes[0] / 3;
    const int n32 = N * 32;
    const int NPAD = ((N + BS - 1) / BS) * BS;
    const int NR = (N + 127) / 128;         // ranges of 128 dsts
    const int NRP = ((NR + 15) / 16) * 16;  // padded (<= 1024)
    const int NB1 = (E + K1_EDGES - 1) / K1_EDGES;
    const int BH = NB1 * NRP;

    int* blockHist = (int*)d_ws;              // BH
    int* off = blockHist + BH;                // BH
    int* total = off + BH;                    // NRP
    int* rangeBase = total + NRP;             // NRP
    int2* sedgeB = (int2*)(rangeBase + NRP);  // E (range-grouped edges)
    float* aggA = (float*)(sedgeB + E);       // n32 (layer-1 h, relu'd float)
    unsigned* Ubf = (unsigned*)(aggA + n32);  // NPAD*16 (bf16-packed U)
    float* Vbuf = (float*)(Ubf + (size_t)NPAD * 16);  // n32
    unsigned* WbtG = (unsigned*)(Vbuf + n32);         // 1024 dw (2 layers x 512)

    const int NBn = (N + BS - 1) / BS;

    // fused: hist | prep1 | Wbt pack (mutually independent)
    setup_kernel<<<NB1 + NBn + 1, BS, 0, stream>>>(ei, E, NRP, blockHist, pos, W1, b1, Ubf,
                                                   Vbuf, N, NB1, NBn, W2, W4, WbtG);
    off_scan_kernel<<<(NRP * 64 + 511) / 512, 512, 0, stream>>>(blockHist, NB1, NRP, off,
                                                                total);
    range_scan_kernel<<<1, 1024, 0, stream>>>(total, NRP, rangeBase);
    bucket_scatter_kernel<<<NB1, BS, 0, stream>>>(ei, E, NRP, off, rangeBase, sedgeB);

    // --- layer 1 ---
    edge_range_kernel<<<NR, EBS, 0, stream>>>(Ubf, (const float4*)Vbuf, sedgeB, rangeBase,
                                              total, WbtG, b2, aggA, N);
    // --- layer 2 ---
    prep2_kernel<<<NBn, BS, 0, stream>>>(pos, aggA, W3, b3, Ubf, Vbuf, N);
    edge_range_kernel<<<NR, EBS, 0, stream>>>(Ubf, (const float4*)Vbuf, sedgeB, rangeBase,
                                              total, WbtG + 512, b4, (float*)d_out, N);
}